// Round 7
// baseline (403.271 us; speedup 1.0000x reference)
//
#include <hip/hip_runtime.h>

// B=256, T=2048, D_IN=64, D_H=64, D_OUT=1
#define TSEQ  2048
#define DH    64
#define CHUNK 64
#define NPROD 3   // producer waves

typedef _Float16 h2     __attribute__((ext_vector_type(2)));
typedef __fp16   fp16x2 __attribute__((ext_vector_type(2)));

union U2H { unsigned u; h2 h; fp16x2 f; };

__device__ inline float fdot2(h2 a, h2 b, float c) {
    return __builtin_amdgcn_fdot2(a, b, c, false);
}

__global__ __launch_bounds__(64 * (NPROD + 1), 1)
void rnn_rl(const float* __restrict__ x, const int* __restrict__ slen,
            const float* __restrict__ W_xh, const float* __restrict__ W_hh,
            const float* __restrict__ W_out, const float* __restrict__ b_out,
            float* __restrict__ out)
{
    __shared__ float a_buf[2][CHUNK][DH];            // 32 KiB double buffer

    const int b   = blockIdx.x;
    const int wv  = threadIdx.x >> 6;
    const int l   = threadIdx.x & 63;
    const int L   = slen[b];
    const int nch = (L + CHUNK - 1) / CHUNK;

    const float* __restrict__ xb = x + (size_t)b * TSEQ * DH;

    if (wv == 0) {
        // ---------------- consumer: the serial chain ----------------
        // Lane l owns W_hh row l as 32 consecutive f16 pairs (RTE converts).
        h2 w[32];
        #pragma unroll
        for (int m = 0; m < 32; ++m) {
            w[m].x = (_Float16)W_hh[l * DH + 2 * m];
            w[m].y = (_Float16)W_hh[l * DH + 2 * m + 1];
        }
        float h = 0.f;
        __syncthreads();             // matches producers' post-produce(0) barrier

        auto step = [&](const float* __restrict__ ap) {
            const float aval = *ap;                   // a_t[l], off-chain ds_read
            // pk (even lanes) = (f16(h[2m]), f16(h[2m+1]))
            const unsigned hx = __float_as_uint(h);
            const unsigned tx = (unsigned)__builtin_amdgcn_mov_dpp(
                                    (int)hx, 0xB1 /*quad_perm XOR1*/, 0xF, 0xF, true);
            U2H pk; pk.f = __builtin_amdgcn_cvt_pkrtz(h, __uint_as_float(tx));
            float a0 = aval, a1 = 0.f, a2 = 0.f, a3 = 0.f;
            #pragma unroll
            for (int m = 0; m < 32; m += 4) {
                // v_readlane -> SGPR pair, folds as the one SGPR src of v_dot2
                U2H s0; s0.u = (unsigned)__builtin_amdgcn_readlane(pk.u, 2 * m + 0);
                U2H s1; s1.u = (unsigned)__builtin_amdgcn_readlane(pk.u, 2 * m + 2);
                U2H s2; s2.u = (unsigned)__builtin_amdgcn_readlane(pk.u, 2 * m + 4);
                U2H s3; s3.u = (unsigned)__builtin_amdgcn_readlane(pk.u, 2 * m + 6);
                a0 = fdot2(s0.h, w[m + 0], a0);
                a1 = fdot2(s1.h, w[m + 1], a1);
                a2 = fdot2(s2.h, w[m + 2], a2);
                a3 = fdot2(s3.h, w[m + 3], a3);
            }
            float z = (a0 + a1) + (a2 + a3);
            // tanh(z) = 1 - 2/(exp(2z)+1)
            z = fminf(fmaxf(z, -15.0f), 15.0f);
            const float e2 = __expf(2.0f * z);
            h = fmaf(-2.0f, __builtin_amdgcn_rcpf(e2 + 1.0f), 1.0f);
            return h;
        };

        for (int c = 0; c < nch; ++c) {
            const int base = c << 6;
            const int cnt  = min(CHUNK, L - base);
            const float* __restrict__ ab = &a_buf[c & 1][0][l];
            if (cnt == CHUNK) {
                #pragma unroll 2
                for (int tt = 0; tt < CHUNK; ++tt) step(ab + tt * DH);
            } else {
                for (int tt = 0; tt < cnt; ++tt) step(ab + tt * DH);
            }
            __syncthreads();
        }

        // out[b] = dot(h_L, W_out[0,:]) + b_out[0]
        float o = h * W_out[l];
        #pragma unroll
        for (int off = 32; off > 0; off >>= 1) o += __shfl_xor(o, off, 64);
        if (l == 0) out[b] = o + b_out[0];
    } else {
        // ---------------- producers: a_t = W_xh @ x_t ----------------
        float wx[DH];
        #pragma unroll
        for (int i = 0; i < DH; ++i) wx[i] = W_xh[l * DH + i];

        auto produce = [&](int pc) {
            const int base = pc << 6;
            const int cnt  = min(CHUNK, L - base);
            for (int tt = wv - 1; tt < cnt; tt += NPROD) {
                const float* __restrict__ xt = xb + (size_t)(base + tt) * DH;
                float s0 = 0.f, s1 = 0.f, s2 = 0.f, s3 = 0.f;
                #pragma unroll
                for (int i = 0; i < DH; i += 4) {
                    s0 = fmaf(wx[i + 0], xt[i + 0], s0);
                    s1 = fmaf(wx[i + 1], xt[i + 1], s1);
                    s2 = fmaf(wx[i + 2], xt[i + 2], s2);
                    s3 = fmaf(wx[i + 3], xt[i + 3], s3);
                }
                a_buf[pc & 1][tt][l] = (s0 + s1) + (s2 + s3);
            }
        };

        if (nch > 0) produce(0);
        __syncthreads();
        for (int c = 0; c < nch; ++c) {
            if (c + 1 < nch) produce(c + 1);
            __syncthreads();
        }
    }
}

extern "C" void kernel_launch(void* const* d_in, const int* in_sizes, int n_in,
                              void* d_out, int out_size, void* d_ws, size_t ws_size,
                              hipStream_t stream) {
    const float* x     = (const float*)d_in[0];
    const int*   slen  = (const int*)  d_in[1];
    const float* W_xh  = (const float*)d_in[2];
    const float* W_hh  = (const float*)d_in[3];
    const float* W_out = (const float*)d_in[4];
    const float* b_out = (const float*)d_in[5];
    float* out = (float*)d_out;

    const int B = in_sizes[1];  // 256
    rnn_rl<<<dim3(B), dim3(64 * (NPROD + 1)), 0, stream>>>(
        x, slen, W_xh, W_hh, W_out, b_out, out);
}